// Round 1
// 608.190 us; speedup vs baseline: 1.4404x; 1.4404x over previous
//
#include <hip/hip_runtime.h>
#include <math.h>

typedef unsigned short u16;
typedef unsigned int   u32;
typedef short bf16x8 __attribute__((ext_vector_type(8)));
typedef float f32x4  __attribute__((ext_vector_type(4)));

// ---------- helpers ----------
__device__ __forceinline__ u16 f2bf(float f) {          // RNE fp32 -> bf16
  u32 u = __builtin_bit_cast(u32, f);
  u32 r = (u + 0x7fffu + ((u >> 16) & 1u)) >> 16;
  return (u16)r;
}
__device__ __forceinline__ float gelu_exact(float v) {
  return 0.5f * v * (1.0f + erff(v * 0.70710678118654752f));
}

// ws layout (bytes): [h bf16 channels-last [b][h][w][200]: 209715200][fw1][fw2]
#define H_BYTES   209715200ll
#define FW1_ELEMS 26624   // 4 kc * 13 nt * 64 lanes * 8
#define FW2_ELEMS 25088   // 7 kc * 7 nt * 64 lanes * 8

// ---------- weight fragment pre-swizzle (UNCHANGED) ----------
// frag element j of lane, tile (kc,nt):  W[o = nt*16 + (lane&15)][c = kc*32 + (lane>>4)*8 + j]
// (A-frag and B-frag lane maps are identical, so this serves either operand role.)
__global__ void prep_frags(const float* __restrict__ w1, const float* __restrict__ w2,
                           u16* __restrict__ fw1, u16* __restrict__ fw2) {
  int gid = blockIdx.x * 256 + threadIdx.x;
  if (gid < FW1_ELEMS) {
    int j = gid & 7, lane = (gid >> 3) & 63, rest = gid >> 9;   // rest = kc*13+nt
    int nt = rest % 13, kc = rest / 13;
    int c = kc * 32 + (lane >> 4) * 8 + j;
    int o = nt * 16 + (lane & 15);
    float v = (c < 100 && o < 200) ? w1[o * 100 + c] : 0.f;
    fw1[gid] = f2bf(v);
  } else if (gid < FW1_ELEMS + FW2_ELEMS) {
    int i2 = gid - FW1_ELEMS;
    int j = i2 & 7, lane = (i2 >> 3) & 63, rest = i2 >> 9;      // rest = kc*7+nt
    int nt = rest % 7, kc = rest / 7;
    int c = kc * 32 + (lane >> 4) * 8 + j;
    int o = nt * 16 + (lane & 15);
    float v = (c < 200 && o < 100) ? w2[o * 200 + c] : 0.f;
    fw2[i2] = f2bf(v);
  }
}

// ---------- conv1: h = gelu(shift5(x) @ w1^T + b1), h stored bf16 channels-last ----------
#define SK1  136   // A-tile k-stride (128 + 8)
#define SKO1 208   // Ot px-stride (u16): 200 outputs + 8 pad
__global__ __launch_bounds__(256, 3) void conv1_kernel(
    const float* __restrict__ x, const u16* __restrict__ fw1,
    const float* __restrict__ b1, u16* __restrict__ hbuf) {
  __shared__ __align__(16) char smem[128 * SKO1 * 2];  // 53248 B: At (34816) then reused as Ot
  u16* At = (u16*)smem;
  u16* Ot = (u16*)smem;
  const int t   = threadIdx.x;
  const int bid = blockIdx.x;
  const int bx  = ((bid & 7) << 9) | (bid >> 3);   // XCD-chunk swizzle: XCD k owns batch k
  const int r  = bx >> 1;            // row id in [0, 8*256)
  const int b  = r >> 8;
  const int hh = r & 255;
  const int w0 = (bx & 1) << 7;      // half-row: 128 px

  // ---- stage shifted x -> bf16 LDS (unchanged, proven) ----
  {
    const int m  = t & 127;
    const int kh = t >> 7;
    const int wp = w0 + m;
    #pragma unroll
    for (int g = 0; g < 8; ++g) {
      const int c0 = 8 * (kh + 2 * g);
      u32 pk[4];
      #pragma unroll
      for (int jj = 0; jj < 8; ++jj) {
        const int c = c0 + jj;
        float v = 0.f;
        if (c < 100) {
          const int dw = (c < 20) ? 1 : ((c < 40) ? -1 : 0);
          const int dh = (c >= 40 && c < 60) ? 1 : ((c >= 60 && c < 80) ? -1 : 0);
          const int hs = hh + dh, ws = wp + dw;
          if ((unsigned)hs < 256u && (unsigned)ws < 256u)
            v = x[((b * 100 + c) * 256 + hs) * 256 + ws];
        }
        const u32 bv = f2bf(v);
        if (jj & 1) pk[jj >> 1] |= bv << 16; else pk[jj >> 1] = bv;
      }
      *(uint4*)&At[m * SK1 + c0] = make_uint4(pk[0], pk[1], pk[2], pk[3]);
    }
  }
  __syncthreads();

  // ---- K loop: SWAPPED operands -> D[o, px] (lane: col=px, rows=4 consecutive o) ----
  const int lane = t & 63, wid = t >> 6;
  const int col = lane & 15, q = lane >> 4;
  f32x4 acc[2][13];
  #pragma unroll
  for (int i = 0; i < 2; ++i)
    #pragma unroll
    for (int nt = 0; nt < 13; ++nt) acc[i][nt] = (f32x4)0.0f;

  const bf16x8* wf = (const bf16x8*)fw1 + lane;
  #pragma unroll 1
  for (int kc = 0; kc < 4; ++kc) {
    const bf16x8 a0 = *(const bf16x8*)&At[((2 * wid + 0) * 16 + col) * SK1 + kc * 32 + q * 8];
    const bf16x8 a1 = *(const bf16x8*)&At[((2 * wid + 1) * 16 + col) * SK1 + kc * 32 + q * 8];
    #pragma unroll
    for (int nt = 0; nt < 13; ++nt) {
      const bf16x8 bf = wf[(kc * 13 + nt) * 64];
      acc[0][nt] = __builtin_amdgcn_mfma_f32_16x16x32_bf16(bf, a0, acc[0][nt], 0, 0, 0);
      acc[1][nt] = __builtin_amdgcn_mfma_f32_16x16x32_bf16(bf, a1, acc[1][nt], 0, 0, 0);
    }
  }

  __syncthreads();   // At dead; smem becomes Ot [px][o]

  // ---- epilogue: bias + gelu, write [px][o] tile, one contiguous global store ----
  #pragma unroll
  for (int nt = 0; nt < 13; ++nt) {
    const int ob = nt * 16 + 4 * q;            // o base for this lane (multiple of 4)
    const float4 bias4 = (ob <= 196) ? *(const float4*)&b1[ob]
                                     : make_float4(0.f, 0.f, 0.f, 0.f);
    #pragma unroll
    for (int i = 0; i < 2; ++i) {
      const f32x4 v = acc[i][nt];
      const int px = (2 * wid + i) * 16 + col;
      const u32 p0 = (u32)f2bf(gelu_exact(v[0] + bias4.x)) |
                     ((u32)f2bf(gelu_exact(v[1] + bias4.y)) << 16);
      const u32 p1 = (u32)f2bf(gelu_exact(v[2] + bias4.z)) |
                     ((u32)f2bf(gelu_exact(v[3] + bias4.w)) << 16);
      *(uint2*)&Ot[px * SKO1 + ob] = make_uint2(p0, p1);
    }
  }
  __syncthreads();
  // 128 px * 200 o * 2B = 51200 B, fully contiguous per block: 3200 uint4 chunks
  {
    const int rowbase = ((b * 256 + hh) * 256 + w0) * 200;   // u16 units
    #pragma unroll
    for (int s = 0; s < 13; ++s) {
      const int id = s * 256 + t;
      if (id < 3200) {
        const int px = id / 25;          // 25 x 16B chunks per pixel
        const int ch = id - px * 25;
        const uint4 d = *(const uint4*)&Ot[px * SKO1 + ch * 8];
        *(uint4*)&hbuf[rowbase + px * 200 + ch * 8] = d;
      }
    }
  }
}

// ---------- conv2: out = shift5(h) @ w2^T + b2 (fp32 out) ----------
#define SK2 232   // A-tile k-stride (224 + 8)
#define PS2 132   // Ob px-stride (f32): 128 + 4
__global__ __launch_bounds__(256, 2) void conv2_kernel(
    const u16* __restrict__ hbuf, const u16* __restrict__ fw2,
    const float* __restrict__ b2, float* __restrict__ out) {
  __shared__ __align__(16) char smem[128 * SK2 * 2];   // 59392 B; At, reused as fp32 Ob[112][132]
  u16*   At = (u16*)smem;
  float* Ob = (float*)smem;                            // 112*132*4 = 59136 B
  const int t   = threadIdx.x;
  const int bid = blockIdx.x;
  const int bx  = ((bid & 7) << 9) | (bid >> 3);   // XCD-chunk swizzle
  const int r  = bx >> 1;
  const int b  = r >> 8;
  const int hh = r & 255;
  const int w0 = (bx & 1) << 7;

  // ---- stage shifted h: channels-last -> 13 independent uint4 loads per thread ----
  {
    const int m  = t & 127;
    const int kh = t >> 7;
    const int wp = w0 + m;
    if (kh == 0) {                       // zero-fill K-pad c 200..223 for this px
      const uint4 z = make_uint4(0u, 0u, 0u, 0u);
      *(uint4*)&At[m * SK2 + 200] = z;
      *(uint4*)&At[m * SK2 + 208] = z;
      *(uint4*)&At[m * SK2 + 216] = z;
    }
    #pragma unroll
    for (int g = 0; g < 13; ++g) {
      const int c0 = 8 * (kh + 2 * g);   // kh=0: 0,16..192; kh=1: 8,24..200(skipped)
      if (c0 < 200) {
        // 8-channel pack lies in one shift group (40 % 8 == 0): uniform (dw,dh)
        const int dw = (c0 < 40) ? 1 : ((c0 < 80) ? -1 : 0);
        const int dh = (c0 >= 80 && c0 < 120) ? 1 : ((c0 >= 120 && c0 < 160) ? -1 : 0);
        const int hs = hh + dh, ws = wp + dw;
        const bool ok = ((unsigned)hs < 256u) && ((unsigned)ws < 256u);
        const int hsc = ok ? hs : hh;    // clamped in-bounds: load unconditionally
        const int wsc = ok ? ws : wp;
        uint4 d = *(const uint4*)&hbuf[((b * 256 + hsc) * 256 + wsc) * 200 + c0];
        if (!ok) d = make_uint4(0u, 0u, 0u, 0u);
        *(uint4*)&At[m * SK2 + c0] = d;
      }
    }
  }
  __syncthreads();

  const int lane = t & 63, wid = t >> 6;
  const int col = lane & 15, q = lane >> 4;
  f32x4 acc[2][7];
  #pragma unroll
  for (int i = 0; i < 2; ++i)
    #pragma unroll
    for (int nt = 0; nt < 7; ++nt) acc[i][nt] = (f32x4)0.0f;

  const bf16x8* wf = (const bf16x8*)fw2 + lane;
  #pragma unroll 1
  for (int kc = 0; kc < 7; ++kc) {
    const bf16x8 a0 = *(const bf16x8*)&At[((2 * wid + 0) * 16 + col) * SK2 + kc * 32 + q * 8];
    const bf16x8 a1 = *(const bf16x8*)&At[((2 * wid + 1) * 16 + col) * SK2 + kc * 32 + q * 8];
    #pragma unroll
    for (int nt = 0; nt < 7; ++nt) {
      const bf16x8 bf = wf[(kc * 7 + nt) * 64];
      acc[0][nt] = __builtin_amdgcn_mfma_f32_16x16x32_bf16(a0, bf, acc[0][nt], 0, 0, 0);
      acc[1][nt] = __builtin_amdgcn_mfma_f32_16x16x32_bf16(a1, bf, acc[1][nt], 0, 0, 0);
    }
  }

  __syncthreads();   // At dead; smem becomes Ob [o][px]

  // ---- epilogue: + b2 into one-shot [o][px] fp32 tile, then coalesced stores ----
  #pragma unroll
  for (int nt = 0; nt < 7; ++nt) {
    const int o = nt * 16 + col;
    const float bias = (o < 100) ? b2[o] : 0.f;
    #pragma unroll
    for (int i = 0; i < 2; ++i) {
      const f32x4 v = acc[i][nt];
      *(float4*)&Ob[o * PS2 + (2 * wid + i) * 16 + 4 * q] =
          make_float4(v[0] + bias, v[1] + bias, v[2] + bias, v[3] + bias);
    }
  }
  __syncthreads();
  {
    const int obase = (b * 100 * 256 + hh) * 256 + w0;
    #pragma unroll
    for (int s = 0; s < 13; ++s) {
      const int id = s * 256 + t;          // 100 oo * 32 chunks = 3200
      if (id < 3200) {
        const int oo = id >> 5, ch = id & 31;
        const float4 d = *(const float4*)&Ob[oo * PS2 + ch * 4];
        *(float4*)&out[obase + oo * 65536 + ch * 4] = d;
      }
    }
  }
}

extern "C" void kernel_launch(void* const* d_in, const int* in_sizes, int n_in,
                              void* d_out, int out_size, void* d_ws, size_t ws_size,
                              hipStream_t stream) {
  const float* x  = (const float*)d_in[0];
  const float* w1 = (const float*)d_in[1];
  const float* b1 = (const float*)d_in[2];
  const float* w2 = (const float*)d_in[3];
  const float* b2 = (const float*)d_in[4];
  float* out = (float*)d_out;

  u16* hbuf = (u16*)d_ws;
  u16* fw1  = (u16*)((char*)d_ws + H_BYTES);
  u16* fw2  = (u16*)((char*)d_ws + H_BYTES + FW1_ELEMS * 2);

  prep_frags<<<202, 256, 0, stream>>>(w1, w2, fw1, fw2);
  conv1_kernel<<<4096, 256, 0, stream>>>(x, fw1, b1, hbuf);
  conv2_kernel<<<4096, 256, 0, stream>>>(hbuf, fw2, b2, out);
}

// Round 2
// 576.298 us; speedup vs baseline: 1.5201x; 1.0553x over previous
//
#include <hip/hip_runtime.h>
#include <math.h>

typedef unsigned short u16;
typedef unsigned int   u32;
typedef short bf16x8 __attribute__((ext_vector_type(8)));
typedef float f32x4  __attribute__((ext_vector_type(4)));

// ---------- helpers ----------
__device__ __forceinline__ u16 f2bf(float f) {          // RNE fp32 -> bf16
  u32 u = __builtin_bit_cast(u32, f);
  u32 r = (u + 0x7fffu + ((u >> 16) & 1u)) >> 16;
  return (u16)r;
}
__device__ __forceinline__ float gelu_exact(float v) {
  return 0.5f * v * (1.0f + erff(v * 0.70710678118654752f));
}

// ws layout (bytes): [h bf16 channels-last [b][h][w][200]: 209715200][fw1][fw2]
#define H_BYTES   209715200ll
#define FW1_ELEMS 26624   // 4 kc * 13 nt * 64 lanes * 8
#define FW2_ELEMS 25088   // 7 kc * 7 nt * 64 lanes * 8

// ---------- weight fragment pre-swizzle (UNCHANGED) ----------
// frag element j of lane, tile (kc,nt):  W[o = nt*16 + (lane&15)][c = kc*32 + (lane>>4)*8 + j]
__global__ void prep_frags(const float* __restrict__ w1, const float* __restrict__ w2,
                           u16* __restrict__ fw1, u16* __restrict__ fw2) {
  int gid = blockIdx.x * 256 + threadIdx.x;
  if (gid < FW1_ELEMS) {
    int j = gid & 7, lane = (gid >> 3) & 63, rest = gid >> 9;   // rest = kc*13+nt
    int nt = rest % 13, kc = rest / 13;
    int c = kc * 32 + (lane >> 4) * 8 + j;
    int o = nt * 16 + (lane & 15);
    float v = (c < 100 && o < 200) ? w1[o * 100 + c] : 0.f;
    fw1[gid] = f2bf(v);
  } else if (gid < FW1_ELEMS + FW2_ELEMS) {
    int i2 = gid - FW1_ELEMS;
    int j = i2 & 7, lane = (i2 >> 3) & 63, rest = i2 >> 9;      // rest = kc*7+nt
    int nt = rest % 7, kc = rest / 7;
    int c = kc * 32 + (lane >> 4) * 8 + j;
    int o = nt * 16 + (lane & 15);
    float v = (c < 200 && o < 100) ? w2[o * 200 + c] : 0.f;
    fw2[i2] = f2bf(v);
  }
}

// ---------- conv1: h = gelu(shift5(x) @ w1^T + b1), h stored bf16 channels-last ----------
// 64-px blocks: acc[1][13] (52 AGPR) + ~68 VGPR -> 4 waves/SIMD with launch_bounds(256,4)
#define SK1  136   // A-tile k-stride (128 + 8): balanced b128 floor
#define SKO1 208   // Ot px-stride (u16): 200 outputs + 8 pad
__global__ __launch_bounds__(256, 4) void conv1_kernel(
    const float* __restrict__ x, const u16* __restrict__ fw1,
    const float* __restrict__ b1, u16* __restrict__ hbuf) {
  __shared__ __align__(16) char smem[64 * SKO1 * 2];   // 26624 B: At (17408) reused as Ot
  u16* At = (u16*)smem;
  u16* Ot = (u16*)smem;
  const int t   = threadIdx.x;
  const int bid = blockIdx.x;
  const int bx  = ((bid & 7) << 10) | (bid >> 3);  // XCD k owns batch k (bijective)
  const int b  = bx >> 10;
  const int hh = (bx >> 2) & 255;
  const int w0 = (bx & 3) << 6;                    // quarter-row: 64 px

  // ---- stage shifted x -> bf16 LDS ----
  {
    const int m  = t & 63;
    const int kh = t >> 6;                          // wave-uniform
    const int wp = w0 + m;
    #pragma unroll
    for (int g = 0; g < 4; ++g) {
      const int c0 = 8 * (kh + 4 * g);              // 0..120 step 8, all 16 packs
      if (c0 >= 100) {                              // 104/112/120: pure K-pad
        *(uint4*)&At[m * SK1 + c0] = make_uint4(0u, 0u, 0u, 0u);
        continue;
      }
      u32 pk[4];
      #pragma unroll
      for (int jj = 0; jj < 8; ++jj) {
        const int c = c0 + jj;
        float v = 0.f;
        if (c < 100) {
          const int dw = (c < 20) ? 1 : ((c < 40) ? -1 : 0);
          const int dh = (c >= 40 && c < 60) ? 1 : ((c >= 60 && c < 80) ? -1 : 0);
          const int hs = hh + dh, ws = wp + dw;
          if ((unsigned)hs < 256u && (unsigned)ws < 256u)
            v = x[((b * 100 + c) * 256 + hs) * 256 + ws];
        }
        const u32 bv = f2bf(v);
        if (jj & 1) pk[jj >> 1] |= bv << 16; else pk[jj >> 1] = bv;
      }
      *(uint4*)&At[m * SK1 + c0] = make_uint4(pk[0], pk[1], pk[2], pk[3]);
    }
  }
  __syncthreads();

  // ---- K loop: swapped operands -> lane holds 4 consecutive o for one px ----
  const int lane = t & 63, wid = t >> 6;
  const int col = lane & 15, q = lane >> 4;
  f32x4 acc[13];
  #pragma unroll
  for (int nt = 0; nt < 13; ++nt) acc[nt] = (f32x4)0.0f;

  const bf16x8* wf = (const bf16x8*)fw1 + lane;
  #pragma unroll 1
  for (int kc = 0; kc < 4; ++kc) {
    const bf16x8 a = *(const bf16x8*)&At[(wid * 16 + col) * SK1 + kc * 32 + q * 8];
    #pragma unroll
    for (int nt = 0; nt < 13; ++nt) {
      const bf16x8 bf = wf[(kc * 13 + nt) * 64];
      acc[nt] = __builtin_amdgcn_mfma_f32_16x16x32_bf16(bf, a, acc[nt], 0, 0, 0);
    }
  }

  __syncthreads();   // At dead; smem becomes Ot [px][o]

  // ---- epilogue: bias + gelu, [px][o] tile, one contiguous global store ----
  #pragma unroll
  for (int nt = 0; nt < 13; ++nt) {
    const int ob = nt * 16 + 4 * q;                // multiple of 4
    const float4 bias4 = (ob <= 196) ? *(const float4*)&b1[ob]
                                     : make_float4(0.f, 0.f, 0.f, 0.f);
    const f32x4 v = acc[nt];
    const int px = wid * 16 + col;
    const u32 p0 = (u32)f2bf(gelu_exact(v[0] + bias4.x)) |
                   ((u32)f2bf(gelu_exact(v[1] + bias4.y)) << 16);
    const u32 p1 = (u32)f2bf(gelu_exact(v[2] + bias4.z)) |
                   ((u32)f2bf(gelu_exact(v[3] + bias4.w)) << 16);
    *(uint2*)&Ot[px * SKO1 + ob] = make_uint2(p0, p1);
  }
  __syncthreads();
  // 64 px * 200 o * 2B = 25600 B contiguous per block: 1600 uint4 chunks
  {
    const int rowbase = ((b * 256 + hh) * 256 + w0) * 200;   // u16 units
    #pragma unroll
    for (int s = 0; s < 7; ++s) {
      const int id = s * 256 + t;
      if (id < 1600) {
        const int px = id / 25;          // 25 x 16B chunks per pixel
        const int ch = id - px * 25;
        const uint4 d = *(const uint4*)&Ot[px * SKO1 + ch * 8];
        *(uint4*)&hbuf[rowbase + px * 200 + ch * 8] = d;
      }
    }
  }
}

// ---------- conv2: out = shift5(h) @ w2^T + b2 (fp32 out) ----------
// 64-px blocks: acc[1][7] (28 AGPR) -> 4 waves/SIMD; LDS 30464 B
#define SK2 232   // A-tile k-stride (224 + 8)
#define PS2 68    // Ob px-stride (f32): 64 + 4
__global__ __launch_bounds__(256, 4) void conv2_kernel(
    const u16* __restrict__ hbuf, const u16* __restrict__ fw2,
    const float* __restrict__ b2, float* __restrict__ out) {
  __shared__ __align__(16) char smem[112 * PS2 * 4];   // 30464 B; At (29696) reused as Ob
  u16*   At = (u16*)smem;
  float* Ob = (float*)smem;
  const int t   = threadIdx.x;
  const int bid = blockIdx.x;
  const int bx  = ((bid & 7) << 10) | (bid >> 3);
  const int b  = bx >> 10;
  const int hh = (bx >> 2) & 255;
  const int w0 = (bx & 3) << 6;

  // ---- stage shifted h: channels-last, 7 independent uint4 loads/thread ----
  {
    const int m  = t & 63;
    const int kh = t >> 6;                          // wave-uniform
    const int wp = w0 + m;
    #pragma unroll
    for (int g = 0; g < 7; ++g) {
      const int c0 = 8 * (kh + 4 * g);              // 0..216 step 8, all 28 packs
      if (c0 >= 200) {                              // 200/208/216: K-pad
        *(uint4*)&At[m * SK2 + c0] = make_uint4(0u, 0u, 0u, 0u);
        continue;
      }
      // 8-channel pack lies in one shift group (40 % 8 == 0): uniform (dw,dh)
      const int dw = (c0 < 40) ? 1 : ((c0 < 80) ? -1 : 0);
      const int dh = (c0 >= 80 && c0 < 120) ? 1 : ((c0 >= 120 && c0 < 160) ? -1 : 0);
      const int hs = hh + dh, ws = wp + dw;
      const bool ok = ((unsigned)hs < 256u) && ((unsigned)ws < 256u);
      const int hsc = ok ? hs : hh;                 // clamped in-bounds, unconditional load
      const int wsc = ok ? ws : wp;
      uint4 d = *(const uint4*)&hbuf[((b * 256 + hsc) * 256 + wsc) * 200 + c0];
      if (!ok) d = make_uint4(0u, 0u, 0u, 0u);
      *(uint4*)&At[m * SK2 + c0] = d;
    }
  }
  __syncthreads();

  const int lane = t & 63, wid = t >> 6;
  const int col = lane & 15, q = lane >> 4;
  f32x4 acc[7];
  #pragma unroll
  for (int nt = 0; nt < 7; ++nt) acc[nt] = (f32x4)0.0f;

  const bf16x8* wf = (const bf16x8*)fw2 + lane;
  #pragma unroll 1
  for (int kc = 0; kc < 7; ++kc) {
    const bf16x8 a = *(const bf16x8*)&At[(wid * 16 + col) * SK2 + kc * 32 + q * 8];
    #pragma unroll
    for (int nt = 0; nt < 7; ++nt) {
      const bf16x8 bf = wf[(kc * 7 + nt) * 64];
      acc[nt] = __builtin_amdgcn_mfma_f32_16x16x32_bf16(a, bf, acc[nt], 0, 0, 0);
    }
  }

  __syncthreads();   // At dead; smem becomes Ob [o][px]

  // ---- epilogue: + b2 into [o][px] fp32 tile, then coalesced stores ----
  #pragma unroll
  for (int nt = 0; nt < 7; ++nt) {
    const int o = nt * 16 + col;
    const float bias = (o < 100) ? b2[o] : 0.f;
    const f32x4 v = acc[nt];
    *(float4*)&Ob[o * PS2 + wid * 16 + 4 * q] =
        make_float4(v[0] + bias, v[1] + bias, v[2] + bias, v[3] + bias);
  }
  __syncthreads();
  {
    const int obase = b * 6553600 + hh * 256 + w0;   // (b*100+oo)*65536 + hh*256 + w0
    #pragma unroll
    for (int s = 0; s < 7; ++s) {
      const int id = s * 256 + t;                    // 100 oo * 16 chunks = 1600
      if (id < 1600) {
        const int oo = id >> 4, ch = id & 15;
        const float4 d = *(const float4*)&Ob[oo * PS2 + ch * 4];
        *(float4*)&out[obase + oo * 65536 + ch * 4] = d;
      }
    }
  }
}

extern "C" void kernel_launch(void* const* d_in, const int* in_sizes, int n_in,
                              void* d_out, int out_size, void* d_ws, size_t ws_size,
                              hipStream_t stream) {
  const float* x  = (const float*)d_in[0];
  const float* w1 = (const float*)d_in[1];
  const float* b1 = (const float*)d_in[2];
  const float* w2 = (const float*)d_in[3];
  const float* b2 = (const float*)d_in[4];
  float* out = (float*)d_out;

  u16* hbuf = (u16*)d_ws;
  u16* fw1  = (u16*)((char*)d_ws + H_BYTES);
  u16* fw2  = (u16*)((char*)d_ws + H_BYTES + FW1_ELEMS * 2);

  prep_frags<<<202, 256, 0, stream>>>(w1, w2, fw1, fw2);
  conv1_kernel<<<8192, 256, 0, stream>>>(x, fw1, b1, hbuf);
  conv2_kernel<<<8192, 256, 0, stream>>>(hbuf, fw2, b2, out);
}